// Round 16
// baseline (149.371 us; speedup 1.0000x reference)
//
#include <hip/hip_runtime.h>
#include <math.h>

// Neural Additive Model: 256 per-feature MLPs 1->128->64->32->1 (ReLU), summed.
// B=8192, fp32 in/out.
//
// Exact rank-table decomposition: pre-relu h2[b,k] = x_b*Sw[r,k] + Sb[r,k],
// r = #(sorted layer-1 thresholds < x_b). Layer 3 on f16 MFMA 32x32x16
// (A=W3^T, B=h2), layer 4 reduced in-register + 1 shfl, 1 atomic/elem.
//
// Round 33: R32's counters explained everything: VGPR stuck at 64 (default
// allocator target = 2 blocks/CU for 1024-thr blocks on this toolchain,
// cf. R14-R17's 512-thr lessons) -> the 16 ping-pong u32x4 buffers SPILLED
// (FETCH 9->36 MB, WRITE 8->40 MB of scratch; 74us). The double-buffer
// theory was never tested. ONE-LINE fix: __launch_bounds__(1024, 1) on
// nam_fused -- 1 block/CU (which the 256-block grid gives anyway), VGPR
// cap 128 (a 1024-thr block needs only 4 waves/SIMD), product 1024 <= 2048
// inside the toolchain's proven-safe regime. Everything else = R32:
// grouped walks + ping-pong gather buffers ga*/gb* so each body's
// lgkmcnt(8) wait leaves the next gather in flight (LGKM in-order),
// 6x-proven shfl + 1-atomic epilogue.

#define NF   256
#define NH1  128
#define NH2  64
#define NH3  32
#define NB   8192

#define NRANK 129
#define ROW4  17                      // uint4 per table row (16 data + 1 pad)
#define ROWH  136                     // halfwords per row

typedef float    f32x16 __attribute__((ext_vector_type(16)));
typedef unsigned u32x4  __attribute__((ext_vector_type(4)));
typedef _Float16 h16x2  __attribute__((ext_vector_type(2)));
typedef _Float16 h16x8  __attribute__((ext_vector_type(8)));

// h2 pair: relu(x*Sw + Sb) on 2 packed f16 channels -> one B-frag dword
__device__ __forceinline__ unsigned pkh2(unsigned sw, unsigned sb, h16x2 xh) {
    h16x2 r = __builtin_elementwise_fma(xh, __builtin_bit_cast(h16x2, sw),
                                            __builtin_bit_cast(h16x2, sb));
    h16x2 hz = {(_Float16)0.f, (_Float16)0.f};
    return __builtin_bit_cast(unsigned, __builtin_elementwise_max(r, hz));
}

// ---------------- transpose: x[B][F] -> xT[F][B] in ws; fuses out-init ----------------
__global__ __launch_bounds__(1024) void transpose_x(
    const float* __restrict__ x, const float* __restrict__ bias,
    float* __restrict__ out, float* __restrict__ xt)
{
    __shared__ float xtile[64][65];        // padded -> conflict-free
    const int t = (int)threadIdx.x;
    const int T = blockIdx.x;              // 0..511
    const int bt = T >> 2, ft = T & 3;     // batch tile 0..127, feat tile 0..3

    if (T < 8) out[T * 1024 + t] = bias[0];   // out poisoned each launch

    #pragma unroll
    for (int it = 0; it < 4; ++it) {
        int idx = t + it * 1024;               // 4096 elems per tile
        int rr = idx >> 6, cc = idx & 63;      // read x[bt*64+rr][ft*64+cc]
        xtile[rr][cc] = x[(size_t)(bt * 64 + rr) * NF + ft * 64 + cc];
    }
    __syncthreads();
    #pragma unroll
    for (int it = 0; it < 4; ++it) {
        int idx = t + it * 1024;
        int cc = idx >> 6, rr = idx & 63;      // write xT[ft*64+cc][bt*64+rr]
        xt[(size_t)(ft * 64 + cc) * NB + bt * 64 + rr] = xtile[rr][cc];
    }
}

// ---------------- fused: one block (1024 thr) per feature, 1 block/CU ----------------
__global__ __launch_bounds__(1024, 1) void nam_fused(
    const float* __restrict__ W1, const float* __restrict__ b1,
    const float* __restrict__ W2, const float* __restrict__ b2,
    const float* __restrict__ W3, const float* __restrict__ b3,
    const float* __restrict__ W4, const float* __restrict__ b4,
    const float* __restrict__ xt,
    float* __restrict__ out)
{
    __shared__ u32x4 SP4[NRANK * ROW4];    // 35.1 KB packed f16 table
    __shared__ float rkey[NH1];            // raw thresholds
    __shared__ float skey[NH1];            // sorted thresholds
    __shared__ int   sidx[NH1];            // sorted payload (channel idx)
    __shared__ float w1s[NH1], b1s[NH1];
    __shared__ float Pbw[16][NH2], Pbb[16][NH2], Pdw[16][NH2], Pdb[16][NH2]; // 16 KB
    __shared__ float lv8[8], lv4[16], lv2[32], lv1[64];  // dense walk levels

    const int f = blockIdx.x;
    const int t = (int)threadIdx.x;
    _Float16* SPh = (_Float16*)SP4;

    // ======== phase 1: build table (R21-proven math) ========
    const float* __restrict__ gw2 = W2 + (size_t)f * NH1 * NH2;
    if (t < NH1) {
        float w  = W1[f * NH1 + t];
        float bb = b1[f * NH1 + t];
        w1s[t] = w; b1s[t] = bb;
        rkey[t] = (w != 0.0f) ? (-bb / w) : INFINITY;   // w==0: never toggled
    }
    __syncthreads();

    // counting-rank sort: 128 threads, each ranks its key vs all 128
    if (t < NH1) {
        const float my = rkey[t];
        int rk = 0;
        #pragma unroll 16
        for (int i = 0; i < NH1; ++i) {
            float ki = rkey[i];
            rk += (ki < my || (ki == my && i < t)) ? 1 : 0;
        }
        skey[rk] = my; sidx[rk] = t;
    }
    __syncthreads();

    // dense walk levels (conflict-free rankof): consecutive addrs -> banks
    if (t < 8)            lv8[t]      = skey[t * 16 + 7];
    else if (t < 24)      lv4[t - 8]  = skey[(t - 8) * 8 + 3];
    else if (t < 56)      lv2[t - 24] = skey[(t - 24) * 4 + 1];
    else if (t < 120)     lv1[t - 56] = skey[(t - 56) * 2];

    // chunked scan: 1024 threads = (k = t&63) x (chunk c = t>>6, 8 j/ranks each)
    {
        const int k = t & 63, c = t >> 6;
        float bw = 0.0f, bbp = 0.0f, dw = 0.0f, db = 0.0f;
        #pragma unroll
        for (int i = 0; i < 8; ++i) {
            int j = c * 8 + i;    // rank-0 base: w<0 active; w==0&&b>0 const-on
            float w = w1s[j], bv = b1s[j], w2v = gw2[j * NH2 + k];
            if (w < 0.0f) { bw = fmaf(w, w2v, bw); bbp = fmaf(bv, w2v, bbp); }
            else if (w == 0.0f && bv > 0.0f) { bbp = fmaf(bv, w2v, bbp); }
            int jj = sidx[c * 8 + i];   // toggle-delta partial
            float ww = w1s[jj], bv2 = b1s[jj], w2x = gw2[jj * NH2 + k];
            float s = (ww > 0.0f) ? 1.0f : ((ww < 0.0f) ? -1.0f : 0.0f);
            dw = fmaf(s * ww,  w2x, dw);
            db = fmaf(s * bv2, w2x, db);
        }
        Pbw[c][k] = bw; Pbb[c][k] = bbp; Pdw[c][k] = dw; Pdb[c][k] = db;
    }
    __syncthreads();
    {
        const int k = t & 63, c = t >> 6;
        float accw = 0.0f;
        float accb = b2[f * NH2 + k];    // b2 seed (round-8 lesson)
        #pragma unroll
        for (int c2 = 0; c2 < 16; ++c2) { accw += Pbw[c2][k]; accb += Pbb[c2][k]; }
        for (int c2 = 0; c2 < c; ++c2) { accw += Pdw[c2][k]; accb += Pdb[c2][k]; }
        // layout per row: Sw halves [0..63], Sb halves [64..127], pad to 136
        if (c == 0) {
            SPh[k]      = (_Float16)accw;          // rank-0 row
            SPh[64 + k] = (_Float16)accb;
        }
        #pragma unroll
        for (int i = 0; i < 8; ++i) {
            int r = c * 8 + i;
            int j = sidx[r];                       // uniform per chunk -> broadcast
            float w = w1s[j], bv = b1s[j], w2v = gw2[j * NH2 + k];
            float s = (w > 0.0f) ? 1.0f : ((w < 0.0f) ? -1.0f : 0.0f);
            accw = fmaf(s * w,  w2v, accw);
            accb = fmaf(s * bv, w2v, accb);
            SPh[(r + 1) * ROWH + k]      = (_Float16)accw;
            SPh[(r + 1) * ROWH + 64 + k] = (_Float16)accb;
        }
    }
    __syncthreads();

    // ======== phase 2: MFMA batch loop, double-buffered register gather ========
    const int lane = t & 63, wv = t >> 6;   // 16 waves
    const int n = lane & 31, q2 = lane >> 5;

    // A-frags: A[m=lane&31][k=(lane>>5)*8+j] = W3[kk][ch=m]; 4 K-tiles of 16
    const float* __restrict__ w3g = W3 + f * NH2 * NH3;
    h16x8 A0, A1, A2, A3;
    #pragma unroll
    for (int j = 0; j < 8; ++j) {
        int kk = q2 * 8 + j;
        A0[j] = (_Float16)w3g[kk * NH3 + n];
        A1[j] = (_Float16)w3g[(kk + 16) * NH3 + n];
        A2[j] = (_Float16)w3g[(kk + 32) * NH3 + n];
        A3[j] = (_Float16)w3g[(kk + 48) * NH3 + n];
    }
    // bacc seeds the first MFMA's C operand; w4r for the layer-4 reduce
    f32x16 bacc;
    float w4r[16];
    #pragma unroll
    for (int reg = 0; reg < 16; ++reg) {
        int row = (reg & 3) + 8 * (reg >> 2) + 4 * q2;
        bacc[reg] = b3[f * NH3 + row];
        w4r[reg]  = W4[f * NH3 + row];
    }
    const float b4f = b4[f];
    const float* __restrict__ xrow = xt + (size_t)f * NB;   // coalesced x
    // register-tree search levels s=64/32/16 (7 thresholds)
    const float t63 = skey[63], t31 = skey[31], t95 = skey[95];
    const float t15 = skey[15], t47 = skey[47], t79 = skey[79], t111 = skey[111];

    // rank = #(skey < q): 3 register levels + 4 conflict-free LDS levels
    auto rankof = [&](float q) -> int {
        int rr = (t63 < q) ? 64 : 0;
        {
            float l1 = (rr & 64) ? t95 : t31;
            if (l1 < q) rr += 32;
            float m0 = (rr & 64) ? t79  : t15;
            float m1 = (rr & 64) ? t111 : t47;
            float l2 = (rr & 32) ? m1 : m0;
            if (l2 < q) rr += 16;
        }
        if (lv8[rr >> 4] < q) rr += 8;
        if (lv4[rr >> 3] < q) rr += 4;
        if (lv2[rr >> 2] < q) rr += 2;
        if (lv1[rr >> 1] < q) rr += 1;
        return rr;
    };

    auto bat = [&](int round) -> int {
        return (((round + f) & 15) * 16 + wv) * 32 + n;
    };

    // one round body; gather regs passed BY VALUE (SSA, regalloc-friendly)
    auto body = [&](int round, float xv,
                    u32x4 s0, u32x4 s1, u32x4 s2, u32x4 s3,
                    u32x4 s4, u32x4 s5, u32x4 s6, u32x4 s7) {
        const int base = (((round + f) & 15) * 16 + wv) * 32;
        const h16x2 xh = {(_Float16)xv, (_Float16)xv};
        u32x4 d0, d1, d2, d3;
        d0.x = pkh2(s0.x, s4.x, xh); d0.y = pkh2(s0.y, s4.y, xh);
        d0.z = pkh2(s0.z, s4.z, xh); d0.w = pkh2(s0.w, s4.w, xh);
        d1.x = pkh2(s1.x, s5.x, xh); d1.y = pkh2(s1.y, s5.y, xh);
        d1.z = pkh2(s1.z, s5.z, xh); d1.w = pkh2(s1.w, s5.w, xh);
        d2.x = pkh2(s2.x, s6.x, xh); d2.y = pkh2(s2.y, s6.y, xh);
        d2.z = pkh2(s2.z, s6.z, xh); d2.w = pkh2(s2.w, s6.w, xh);
        d3.x = pkh2(s3.x, s7.x, xh); d3.y = pkh2(s3.y, s7.y, xh);
        d3.z = pkh2(s3.z, s7.z, xh); d3.w = pkh2(s3.w, s7.w, xh);
        h16x8 B0 = __builtin_bit_cast(h16x8, d0);
        h16x8 B1 = __builtin_bit_cast(h16x8, d1);
        h16x8 B2 = __builtin_bit_cast(h16x8, d2);
        h16x8 B3 = __builtin_bit_cast(h16x8, d3);

        f32x16 acc = __builtin_amdgcn_mfma_f32_32x32x16_f16(A0, B0, bacc, 0, 0, 0);
        acc = __builtin_amdgcn_mfma_f32_32x32x16_f16(A1, B1, acc, 0, 0, 0);
        acc = __builtin_amdgcn_mfma_f32_32x32x16_f16(A2, B2, acc, 0, 0, 0);
        acc = __builtin_amdgcn_mfma_f32_32x32x16_f16(A3, B3, acc, 0, 0, 0);

        float p = 0.0f;
        #pragma unroll
        for (int reg = 0; reg < 16; ++reg)
            p = fmaf(fmaxf(acc[reg], 0.0f), w4r[reg], p);
        p += __shfl_xor(p, 32);
        if (lane < 32) atomicAdd(&out[base + lane], p + b4f);
    };

    // 4 groups x 4 rounds: walks precomputed (R30), gathers ping-pong
    // double-buffered so each body's lgkmcnt(8) leaves the next gather
    // in flight (LGKM is in-order).
    #pragma unroll 1
    for (int g = 0; g < 4; ++g) {
        const int rb = g * 4;
        const float xa = xrow[bat(rb + 0)];
        const float xb = xrow[bat(rb + 1)];
        const float xc = xrow[bat(rb + 2)];
        const float xd = xrow[bat(rb + 3)];
        const int ra  = rankof(xa);
        const int rc2 = rankof(xc);          // interleave: independent walks
        const int rbk = rankof(xb);
        const int rd  = rankof(xd);

        u32x4 ga0, ga1, ga2, ga3, ga4, ga5, ga6, ga7;
        u32x4 gb0, gb1, gb2, gb3, gb4, gb5, gb6, gb7;

        int ro = ra * ROW4;                  // gather A <- round rb+0
        ga0 = SP4[ro + q2];      ga1 = SP4[ro + 2 + q2];
        ga2 = SP4[ro + 4 + q2];  ga3 = SP4[ro + 6 + q2];
        ga4 = SP4[ro + 8 + q2];  ga5 = SP4[ro + 10 + q2];
        ga6 = SP4[ro + 12 + q2]; ga7 = SP4[ro + 14 + q2];

        ro = rbk * ROW4;                     // gather B <- round rb+1
        gb0 = SP4[ro + q2];      gb1 = SP4[ro + 2 + q2];
        gb2 = SP4[ro + 4 + q2];  gb3 = SP4[ro + 6 + q2];
        gb4 = SP4[ro + 8 + q2];  gb5 = SP4[ro + 10 + q2];
        gb6 = SP4[ro + 12 + q2]; gb7 = SP4[ro + 14 + q2];

        body(rb + 0, xa, ga0, ga1, ga2, ga3, ga4, ga5, ga6, ga7);

        ro = rc2 * ROW4;                     // gather A <- round rb+2
        ga0 = SP4[ro + q2];      ga1 = SP4[ro + 2 + q2];
        ga2 = SP4[ro + 4 + q2];  ga3 = SP4[ro + 6 + q2];
        ga4 = SP4[ro + 8 + q2];  ga5 = SP4[ro + 10 + q2];
        ga6 = SP4[ro + 12 + q2]; ga7 = SP4[ro + 14 + q2];

        body(rb + 1, xb, gb0, gb1, gb2, gb3, gb4, gb5, gb6, gb7);

        ro = rd * ROW4;                      // gather B <- round rb+3
        gb0 = SP4[ro + q2];      gb1 = SP4[ro + 2 + q2];
        gb2 = SP4[ro + 4 + q2];  gb3 = SP4[ro + 6 + q2];
        gb4 = SP4[ro + 8 + q2];  gb5 = SP4[ro + 10 + q2];
        gb6 = SP4[ro + 12 + q2]; gb7 = SP4[ro + 14 + q2];

        body(rb + 2, xc, ga0, ga1, ga2, ga3, ga4, ga5, ga6, ga7);
        body(rb + 3, xd, gb0, gb1, gb2, gb3, gb4, gb5, gb6, gb7);
    }
}

extern "C" void kernel_launch(void* const* d_in, const int* in_sizes, int n_in,
                              void* d_out, int out_size, void* d_ws, size_t ws_size,
                              hipStream_t stream) {
    const float* x    = (const float*)d_in[0];
    const float* W1   = (const float*)d_in[1];
    const float* b1   = (const float*)d_in[2];
    const float* W2   = (const float*)d_in[3];
    const float* b2   = (const float*)d_in[4];
    const float* W3   = (const float*)d_in[5];
    const float* b3   = (const float*)d_in[6];
    const float* W4   = (const float*)d_in[7];
    const float* b4   = (const float*)d_in[8];
    const float* bias = (const float*)d_in[9];
    float* out   = (float*)d_out;
    float* xtw   = (float*)d_ws;      // ws holds xT: 8 MB

    // transpose (both sides coalesced) + out-init
    transpose_x<<<512, 1024, 0, stream>>>(x, bias, out, xtw);
    // fused: 1 block/feature = 1 block/CU; table lives and dies in LDS
    nam_fused<<<NF, 1024, 0, stream>>>(W1, b1, W2, b2, W3, b3, W4, b4,
                                       xtw, out);
}

// Round 17
// 110.909 us; speedup vs baseline: 1.3468x; 1.3468x over previous
//
#include <hip/hip_runtime.h>
#include <math.h>

// Neural Additive Model: 256 per-feature MLPs 1->128->64->32->1 (ReLU), summed.
// B=8192, fp32 in/out.
//
// Exact rank-table decomposition: pre-relu h2[b,k] = x_b*Sw[r,k] + Sb[r,k],
// r = #(sorted layer-1 thresholds < x_b). Layer 3 on f16 MFMA 32x32x16
// (A=W3^T, B=h2), layer 4 reduced in-register + 1 shfl, 1 atomic/elem.
//
// Round 34: REVERT to R30 (110.2us, proven best). The double-buffered
// gather branch is CLOSED: R32 and R33 both show the allocator hard-caps
// 1024-thr blocks at 64 VGPR on this toolchain (launch_bounds(1024,1)
// ignored), so the 16 ping-pong u32x4 buffers spill to scratch (FETCH
// 36MB/WRITE 40MB, 74us) -- the construct is unbuildable here, not null.
// R30's structure: R21 two-kernel (transpose_x + fused 1 block/feature),
// 17-uint4 table + b128 gather, dense walk levels, GROUPED rank walks
// (4 independent walks pipelined per group of 4 rounds -- the one proven
// latency win, -2us), 6x-proven shfl + 1-atomic epilogue.
// Evidence says this is the floor: phase 2 is bound by per-CU LDS
// latency/throughput with inherently data-dependent gather addresses
// (R23 occupancy null, R25/R27 nulls, R28 sort -16x conflicts but +81us
// scatter, R26/R31-33 prefetch spill-blocked). Remaining dur_us is
// ~43us harness poison fill + ~3.5us transpose + ~42us fused + gaps.

#define NF   256
#define NH1  128
#define NH2  64
#define NH3  32
#define NB   8192

#define NRANK 129
#define ROW4  17                      // uint4 per table row (16 data + 1 pad)
#define ROWH  136                     // halfwords per row

typedef float    f32x16 __attribute__((ext_vector_type(16)));
typedef unsigned u32x4  __attribute__((ext_vector_type(4)));
typedef _Float16 h16x2  __attribute__((ext_vector_type(2)));
typedef _Float16 h16x8  __attribute__((ext_vector_type(8)));

// h2 pair: relu(x*Sw + Sb) on 2 packed f16 channels -> one B-frag dword
__device__ __forceinline__ unsigned pkh2(unsigned sw, unsigned sb, h16x2 xh) {
    h16x2 r = __builtin_elementwise_fma(xh, __builtin_bit_cast(h16x2, sw),
                                            __builtin_bit_cast(h16x2, sb));
    h16x2 hz = {(_Float16)0.f, (_Float16)0.f};
    return __builtin_bit_cast(unsigned, __builtin_elementwise_max(r, hz));
}

// ---------------- transpose: x[B][F] -> xT[F][B] in ws; fuses out-init ----------------
__global__ __launch_bounds__(1024) void transpose_x(
    const float* __restrict__ x, const float* __restrict__ bias,
    float* __restrict__ out, float* __restrict__ xt)
{
    __shared__ float xtile[64][65];        // padded -> conflict-free
    const int t = (int)threadIdx.x;
    const int T = blockIdx.x;              // 0..511
    const int bt = T >> 2, ft = T & 3;     // batch tile 0..127, feat tile 0..3

    if (T < 8) out[T * 1024 + t] = bias[0];   // out poisoned each launch

    #pragma unroll
    for (int it = 0; it < 4; ++it) {
        int idx = t + it * 1024;               // 4096 elems per tile
        int rr = idx >> 6, cc = idx & 63;      // read x[bt*64+rr][ft*64+cc]
        xtile[rr][cc] = x[(size_t)(bt * 64 + rr) * NF + ft * 64 + cc];
    }
    __syncthreads();
    #pragma unroll
    for (int it = 0; it < 4; ++it) {
        int idx = t + it * 1024;
        int cc = idx >> 6, rr = idx & 63;      // write xT[ft*64+cc][bt*64+rr]
        xt[(size_t)(ft * 64 + cc) * NB + bt * 64 + rr] = xtile[rr][cc];
    }
}

// ---------------- fused: one block (1024 thr) per feature ----------------
__global__ __launch_bounds__(1024) void nam_fused(
    const float* __restrict__ W1, const float* __restrict__ b1,
    const float* __restrict__ W2, const float* __restrict__ b2,
    const float* __restrict__ W3, const float* __restrict__ b3,
    const float* __restrict__ W4, const float* __restrict__ b4,
    const float* __restrict__ xt,
    float* __restrict__ out)
{
    __shared__ u32x4 SP4[NRANK * ROW4];    // 35.1 KB packed f16 table
    __shared__ float rkey[NH1];            // raw thresholds
    __shared__ float skey[NH1];            // sorted thresholds
    __shared__ int   sidx[NH1];            // sorted payload (channel idx)
    __shared__ float w1s[NH1], b1s[NH1];
    __shared__ float Pbw[16][NH2], Pbb[16][NH2], Pdw[16][NH2], Pdb[16][NH2]; // 16 KB
    __shared__ float lv8[8], lv4[16], lv2[32], lv1[64];  // dense walk levels

    const int f = blockIdx.x;
    const int t = (int)threadIdx.x;
    _Float16* SPh = (_Float16*)SP4;

    // ======== phase 1: build table (R21-proven math) ========
    const float* __restrict__ gw2 = W2 + (size_t)f * NH1 * NH2;
    if (t < NH1) {
        float w  = W1[f * NH1 + t];
        float bb = b1[f * NH1 + t];
        w1s[t] = w; b1s[t] = bb;
        rkey[t] = (w != 0.0f) ? (-bb / w) : INFINITY;   // w==0: never toggled
    }
    __syncthreads();

    // counting-rank sort: 128 threads, each ranks its key vs all 128
    if (t < NH1) {
        const float my = rkey[t];
        int rk = 0;
        #pragma unroll 16
        for (int i = 0; i < NH1; ++i) {
            float ki = rkey[i];
            rk += (ki < my || (ki == my && i < t)) ? 1 : 0;
        }
        skey[rk] = my; sidx[rk] = t;
    }
    __syncthreads();

    // dense walk levels (conflict-free rankof): consecutive addrs -> banks
    if (t < 8)            lv8[t]      = skey[t * 16 + 7];
    else if (t < 24)      lv4[t - 8]  = skey[(t - 8) * 8 + 3];
    else if (t < 56)      lv2[t - 24] = skey[(t - 24) * 4 + 1];
    else if (t < 120)     lv1[t - 56] = skey[(t - 56) * 2];

    // chunked scan: 1024 threads = (k = t&63) x (chunk c = t>>6, 8 j/ranks each)
    {
        const int k = t & 63, c = t >> 6;
        float bw = 0.0f, bbp = 0.0f, dw = 0.0f, db = 0.0f;
        #pragma unroll
        for (int i = 0; i < 8; ++i) {
            int j = c * 8 + i;    // rank-0 base: w<0 active; w==0&&b>0 const-on
            float w = w1s[j], bv = b1s[j], w2v = gw2[j * NH2 + k];
            if (w < 0.0f) { bw = fmaf(w, w2v, bw); bbp = fmaf(bv, w2v, bbp); }
            else if (w == 0.0f && bv > 0.0f) { bbp = fmaf(bv, w2v, bbp); }
            int jj = sidx[c * 8 + i];   // toggle-delta partial
            float ww = w1s[jj], bv2 = b1s[jj], w2x = gw2[jj * NH2 + k];
            float s = (ww > 0.0f) ? 1.0f : ((ww < 0.0f) ? -1.0f : 0.0f);
            dw = fmaf(s * ww,  w2x, dw);
            db = fmaf(s * bv2, w2x, db);
        }
        Pbw[c][k] = bw; Pbb[c][k] = bbp; Pdw[c][k] = dw; Pdb[c][k] = db;
    }
    __syncthreads();
    {
        const int k = t & 63, c = t >> 6;
        float accw = 0.0f;
        float accb = b2[f * NH2 + k];    // b2 seed (round-8 lesson)
        #pragma unroll
        for (int c2 = 0; c2 < 16; ++c2) { accw += Pbw[c2][k]; accb += Pbb[c2][k]; }
        for (int c2 = 0; c2 < c; ++c2) { accw += Pdw[c2][k]; accb += Pdb[c2][k]; }
        // layout per row: Sw halves [0..63], Sb halves [64..127], pad to 136
        if (c == 0) {
            SPh[k]      = (_Float16)accw;          // rank-0 row
            SPh[64 + k] = (_Float16)accb;
        }
        #pragma unroll
        for (int i = 0; i < 8; ++i) {
            int r = c * 8 + i;
            int j = sidx[r];                       // uniform per chunk -> broadcast
            float w = w1s[j], bv = b1s[j], w2v = gw2[j * NH2 + k];
            float s = (w > 0.0f) ? 1.0f : ((w < 0.0f) ? -1.0f : 0.0f);
            accw = fmaf(s * w,  w2v, accw);
            accb = fmaf(s * bv, w2v, accb);
            SPh[(r + 1) * ROWH + k]      = (_Float16)accw;
            SPh[(r + 1) * ROWH + 64 + k] = (_Float16)accb;
        }
    }
    __syncthreads();

    // ======== phase 2: MFMA batch loop, walks precomputed per group of 4 ========
    const int lane = t & 63, wv = t >> 6;   // 16 waves
    const int n = lane & 31, q2 = lane >> 5;

    // A-frags: A[m=lane&31][k=(lane>>5)*8+j] = W3[kk][ch=m]; 4 K-tiles of 16
    const float* __restrict__ w3g = W3 + f * NH2 * NH3;
    h16x8 A0, A1, A2, A3;
    #pragma unroll
    for (int j = 0; j < 8; ++j) {
        int kk = q2 * 8 + j;
        A0[j] = (_Float16)w3g[kk * NH3 + n];
        A1[j] = (_Float16)w3g[(kk + 16) * NH3 + n];
        A2[j] = (_Float16)w3g[(kk + 32) * NH3 + n];
        A3[j] = (_Float16)w3g[(kk + 48) * NH3 + n];
    }
    // bacc seeds the first MFMA's C operand; w4r for the layer-4 reduce
    f32x16 bacc;
    float w4r[16];
    #pragma unroll
    for (int reg = 0; reg < 16; ++reg) {
        int row = (reg & 3) + 8 * (reg >> 2) + 4 * q2;
        bacc[reg] = b3[f * NH3 + row];
        w4r[reg]  = W4[f * NH3 + row];
    }
    const float b4f = b4[f];
    const float* __restrict__ xrow = xt + (size_t)f * NB;   // coalesced x
    // register-tree search levels s=64/32/16 (7 thresholds)
    const float t63 = skey[63], t31 = skey[31], t95 = skey[95];
    const float t15 = skey[15], t47 = skey[47], t79 = skey[79], t111 = skey[111];

    // rank = #(skey < q): 3 register levels + 4 conflict-free LDS levels
    auto rankof = [&](float q) -> int {
        int rr = (t63 < q) ? 64 : 0;
        {
            float l1 = (rr & 64) ? t95 : t31;
            if (l1 < q) rr += 32;
            float m0 = (rr & 64) ? t79  : t15;
            float m1 = (rr & 64) ? t111 : t47;
            float l2 = (rr & 32) ? m1 : m0;
            if (l2 < q) rr += 16;
        }
        if (lv8[rr >> 4] < q) rr += 8;
        if (lv4[rr >> 3] < q) rr += 4;
        if (lv2[rr >> 2] < q) rr += 2;
        if (lv1[rr >> 1] < q) rr += 1;
        return rr;
    };

    auto bat = [&](int round) -> int {
        return (((round + f) & 15) * 16 + wv) * 32 + n;
    };

    // one round body (static args; compiler inlines)
    auto round_body = [&](int round, float xv, int r) {
        const int base = (((round + f) & 15) * 16 + wv) * 32;
        const int ro = r * ROW4;
        u32x4 SW0 = SP4[ro + q2],      SW1 = SP4[ro + 2 + q2];
        u32x4 SW2 = SP4[ro + 4 + q2],  SW3 = SP4[ro + 6 + q2];
        u32x4 SB0 = SP4[ro + 8 + q2],  SB1 = SP4[ro + 10 + q2];
        u32x4 SB2 = SP4[ro + 12 + q2], SB3 = SP4[ro + 14 + q2];

        const h16x2 xh = {(_Float16)xv, (_Float16)xv};
        u32x4 d0, d1, d2, d3;
        d0.x = pkh2(SW0.x, SB0.x, xh); d0.y = pkh2(SW0.y, SB0.y, xh);
        d0.z = pkh2(SW0.z, SB0.z, xh); d0.w = pkh2(SW0.w, SB0.w, xh);
        d1.x = pkh2(SW1.x, SB1.x, xh); d1.y = pkh2(SW1.y, SB1.y, xh);
        d1.z = pkh2(SW1.z, SB1.z, xh); d1.w = pkh2(SW1.w, SB1.w, xh);
        d2.x = pkh2(SW2.x, SB2.x, xh); d2.y = pkh2(SW2.y, SB2.y, xh);
        d2.z = pkh2(SW2.z, SB2.z, xh); d2.w = pkh2(SW2.w, SB2.w, xh);
        d3.x = pkh2(SW3.x, SB3.x, xh); d3.y = pkh2(SW3.y, SB3.y, xh);
        d3.z = pkh2(SW3.z, SB3.z, xh); d3.w = pkh2(SW3.w, SB3.w, xh);
        h16x8 B0 = __builtin_bit_cast(h16x8, d0);
        h16x8 B1 = __builtin_bit_cast(h16x8, d1);
        h16x8 B2 = __builtin_bit_cast(h16x8, d2);
        h16x8 B3 = __builtin_bit_cast(h16x8, d3);

        f32x16 acc = __builtin_amdgcn_mfma_f32_32x32x16_f16(A0, B0, bacc, 0, 0, 0);
        acc = __builtin_amdgcn_mfma_f32_32x32x16_f16(A1, B1, acc, 0, 0, 0);
        acc = __builtin_amdgcn_mfma_f32_32x32x16_f16(A2, B2, acc, 0, 0, 0);
        acc = __builtin_amdgcn_mfma_f32_32x32x16_f16(A3, B3, acc, 0, 0, 0);

        float p = 0.0f;
        #pragma unroll
        for (int reg = 0; reg < 16; ++reg)
            p = fmaf(fmaxf(acc[reg], 0.0f), w4r[reg], p);
        p += __shfl_xor(p, 32);
        if (lane < 32) atomicAdd(&out[base + lane], p + b4f);
    };

    // 4 groups x 4 rounds: x-loads then 4 INDEPENDENT walks (pipeline at
    // LDS throughput, not 4x480cy serial), then 4 static round bodies.
    #pragma unroll 1
    for (int g = 0; g < 4; ++g) {
        const int rb = g * 4;
        const float xa = xrow[bat(rb + 0)];
        const float xb = xrow[bat(rb + 1)];
        const float xc = xrow[bat(rb + 2)];
        const float xd = xrow[bat(rb + 3)];
        const int ra = rankof(xa);
        const int rc2 = rankof(xc);          // interleave: independent walks
        const int rbk = rankof(xb);
        const int rd = rankof(xd);

        round_body(rb + 0, xa, ra);
        round_body(rb + 1, xb, rbk);
        round_body(rb + 2, xc, rc2);
        round_body(rb + 3, xd, rd);
    }
}

extern "C" void kernel_launch(void* const* d_in, const int* in_sizes, int n_in,
                              void* d_out, int out_size, void* d_ws, size_t ws_size,
                              hipStream_t stream) {
    const float* x    = (const float*)d_in[0];
    const float* W1   = (const float*)d_in[1];
    const float* b1   = (const float*)d_in[2];
    const float* W2   = (const float*)d_in[3];
    const float* b2   = (const float*)d_in[4];
    const float* W3   = (const float*)d_in[5];
    const float* b3   = (const float*)d_in[6];
    const float* W4   = (const float*)d_in[7];
    const float* b4   = (const float*)d_in[8];
    const float* bias = (const float*)d_in[9];
    float* out   = (float*)d_out;
    float* xtw   = (float*)d_ws;      // ws holds xT: 8 MB

    // transpose (both sides coalesced) + out-init
    transpose_x<<<512, 1024, 0, stream>>>(x, bias, out, xtw);
    // fused: 1 block/feature = 1 block/CU; table lives and dies in LDS
    nam_fused<<<NF, 1024, 0, stream>>>(W1, b1, W2, b2, W3, b3, W4, b4,
                                       xtw, out);
}